// Round 1
// baseline (89.666 us; speedup 1.0000x reference)
//
#include <hip/hip_runtime.h>
#include <hip/hip_bf16.h>

using short8  = __attribute__((ext_vector_type(8))) short;   // 8 bf16 (4 VGPRs)
using floatx4 = __attribute__((ext_vector_type(4))) float;   // 4 fp32 acc

#define B_ROWS 4096
#define NTOT   8192
#define DD     128
#define SQRTC1 1.6986436f            // sqrt(2*log2(e)) — pre-scale so MFMA yields C1*dot
#define E2f    7.389056098930650f    // exp(2): diagonal term (self-dot) to subtract
#define LN2f   0.6931471805599453f   // 2p = d' * ln2  (d' = C1 * p)

// async global->LDS DMA, 16B per lane; LDS dest must be wave-uniform base + lane*16
#define GLOAD_LDS16(gptr, lptr)                                                          \
    __builtin_amdgcn_global_load_lds((const __attribute__((address_space(1))) void*)(gptr), \
                                     (__attribute__((address_space(3))) void*)(lptr), 16, 0, 0)

// ---------------- kernel 1: L2-normalize rows, scale by sqrt(C1), cast bf16 ----------------
__global__ __launch_bounds__(256) void nrm_kernel(const float* __restrict__ zi,
                                                  const float* __restrict__ zj,
                                                  __hip_bfloat16* __restrict__ zb) {
    int tid  = threadIdx.x;
    int wave = tid >> 6, lane = tid & 63;
    int row  = blockIdx.x * 4 + wave;
    const float* src = (row < B_ROWS) ? (zi + (size_t)row * DD)
                                      : (zj + (size_t)(row - B_ROWS) * DD);
    float2 v = *(const float2*)(src + lane * 2);
    float s = v.x * v.x + v.y * v.y;
    #pragma unroll
    for (int m = 1; m <= 32; m <<= 1) s += __shfl_xor(s, m, 64);
    float scale = SQRTC1 / fmaxf(sqrtf(s), 1e-12f);
    __hip_bfloat162 h2;
    h2.x = __float2bfloat16(v.x * scale);
    h2.y = __float2bfloat16(v.y * scale);
    *(__hip_bfloat162*)(zb + (size_t)row * DD + lane * 2) = h2;   // one 4B store
}

// ---------------- kernel 2: fused sim-GEMM + partial sum of exp2 ----------------
// grid (32 row-tiles, 32 col-splits); block 256 = 4 waves. Block tile 256x256.
// Wave w: rows [r0+w*64, +64) as 4 row-fragments, full K=128 resident (64 VGPRs).
// B tiles (64 cols) DMA'd to LDS via global_load_lds, double-buffered, 1 barrier/tile.
// LDS chunk layout [kc8][col^swz]: chunk slot c holds global col (c&63)^(((c>>6)&3)<<1),
// k-bytes [(c>>6)*16, +16).  The XOR swizzle (pre-swizzled GLOBAL source; LDS dest stays
// linear as global_load_lds requires) spreads the 4 q-groups across bank quads on the
// read side: bank quad = (n16 ^ (q<<1))&7 -> 2-way instead of 8-way conflict.
// __launch_bounds__(256,3): 170-VGPR cap (demand ~130) — (256,4)'s 128-cap forced spills.
__global__ __launch_bounds__(256, 3) void sim_kernel(const __hip_bfloat16* __restrict__ zbf,
                                                     float* __restrict__ lpart) {
    __shared__ uint4 ldsB[2][1024];     // 2 x 16 KB
    const short* zs = (const short*)zbf;

    int tid = threadIdx.x;
    int w   = tid >> 6, lane = tid & 63;
    int q   = lane >> 4, n16 = lane & 15;
    int r0  = blockIdx.x * 256 + w * 64;
    int cq  = blockIdx.y;

    // A fragments: rows r0+rs*16+n16, k-chunk kc: m = lane&15, k = (lane>>4)*8 + j
    short8 af[4][4];
    #pragma unroll
    for (int rs = 0; rs < 4; ++rs) {
        const short* ap = zs + (size_t)(r0 + rs * 16 + n16) * DD + q * 8;
        #pragma unroll
        for (int kc = 0; kc < 4; ++kc)
            af[rs][kc] = *(const short8*)(ap + kc * 32);
    }

    // staging: thread owns LDS slots c = tid + 256*rr (linear dest, wave-uniform+lane*16).
    // global source column is XOR-swizzled: scol = (tid&63) ^ (w<<1)  (since (c>>6)&3 == w)
    int scol = (tid & 63) ^ (w << 1);
    const short* gcol = zs + (size_t)(cq * 256 + scol) * DD + w * 8;

    float l[4][4];
    #pragma unroll
    for (int rs = 0; rs < 4; ++rs)
        #pragma unroll
        for (int r = 0; r < 4; ++r) l[rs][r] = 0.f;

    // prologue: stage tile 0 into buf 0
    #pragma unroll
    for (int rr = 0; rr < 4; ++rr)
        GLOAD_LDS16(gcol + rr * 32, &ldsB[0][tid + 256 * rr]);
    __syncthreads();   // compiler drains vmcnt before s_barrier

    for (int t = 0; t < 4; ++t) {          // rolled: keeps staging addr math to one live copy
        // issue next tile's DMA into the other buffer (overlaps with compute below)
        if (t < 3) {
            const short* gn = gcol + (size_t)(t + 1) * 64 * DD;
            #pragma unroll
            for (int rr = 0; rr < 4; ++rr)
                GLOAD_LDS16(gn + rr * 32, &ldsB[(t + 1) & 1][tid + 256 * rr]);
        }
        const uint4* Lb = ldsB[t & 1];
        #pragma unroll
        for (int st = 0; st < 4; ++st) {
            floatx4 acc[4];
            #pragma unroll
            for (int rs = 0; rs < 4; ++rs) acc[rs] = (floatx4){0.f, 0.f, 0.f, 0.f};
            #pragma unroll
            for (int kc = 0; kc < 4; ++kc) {
                // B frag: col = st*16+n16, k-chunk16B = kc*4+q
                // swizzled slot = (kc*4+q)*64 + st*16 + (n16 ^ (q<<1))
                short8 bf = *(const short8*)&Lb[(kc * 4 + q) * 64 + st * 16 + (n16 ^ (q << 1))];
                #pragma unroll
                for (int rs = 0; rs < 4; ++rs)
                    acc[rs] = __builtin_amdgcn_mfma_f32_16x16x32_bf16(af[rs][kc], bf, acc[rs], 0, 0, 0);
            }
            // epilogue: exp2 + add per element (C layout: row = q*4+r, col = n16)
            #pragma unroll
            for (int rs = 0; rs < 4; ++rs)
                #pragma unroll
                for (int r = 0; r < 4; ++r)
                    l[rs][r] += __builtin_amdgcn_exp2f(acc[rs][r]);
        }
        __syncthreads();   // drains next tile's DMA + releases this buffer
    }

    // reduce the 16 column-lanes (lanes sharing q hold the same 4 rows)
    #pragma unroll
    for (int rs = 0; rs < 4; ++rs)
        #pragma unroll
        for (int r = 0; r < 4; ++r) {
            float v = l[rs][r];
            v += __shfl_xor(v, 1, 64);
            v += __shfl_xor(v, 2, 64);
            v += __shfl_xor(v, 4, 64);
            v += __shfl_xor(v, 8, 64);
            l[rs][r] = v;
        }
    if (n16 == 0) {
        #pragma unroll
        for (int rs = 0; rs < 4; ++rs)
            #pragma unroll
            for (int r = 0; r < 4; ++r) {
                int row = r0 + rs * 16 + q * 4 + r;
                lpart[row * 32 + cq] = l[rs][r];
            }
    }
}

// ---------------- kernel 3: finalize ----------------
// loss_i = -d'*ln2 + ln(sum_exp2 - e^2); mean via block reduce + 32 atomics
__global__ __launch_bounds__(256) void fin_kernel(const __hip_bfloat16* __restrict__ zbf,
                                                  const float* __restrict__ lpart,
                                                  float* __restrict__ out) {
    __shared__ float red[256];
    int row = blockIdx.x * 256 + threadIdx.x;

    const float4* lp = (const float4*)(lpart + row * 32);
    float l = 0.f;
    #pragma unroll
    for (int i = 0; i < 8; ++i) { float4 v = lp[i]; l += (v.x + v.y) + (v.z + v.w); }

    const __hip_bfloat162* a = (const __hip_bfloat162*)(zbf + (size_t)row * DD);
    const __hip_bfloat162* b = (const __hip_bfloat162*)(zbf + (size_t)(row ^ B_ROWS) * DD);
    float d = 0.f;
    #pragma unroll
    for (int i = 0; i < 64; ++i) {
        float2 av = __bfloat1622float2(a[i]);
        float2 bv = __bfloat1622float2(b[i]);
        d += av.x * bv.x + av.y * bv.y;
    }

    float loss = -d * LN2f + logf(l - E2f);
    red[threadIdx.x] = loss;
    __syncthreads();
    #pragma unroll
    for (int s = 128; s > 0; s >>= 1) {
        if (threadIdx.x < s) red[threadIdx.x] += red[threadIdx.x + s];
        __syncthreads();
    }
    if (threadIdx.x == 0) atomicAdd(out, red[0] * (1.0f / (float)NTOT));
}

extern "C" void kernel_launch(void* const* d_in, const int* in_sizes, int n_in,
                              void* d_out, int out_size, void* d_ws, size_t ws_size,
                              hipStream_t stream) {
    const float* zi = (const float*)d_in[0];
    const float* zj = (const float*)d_in[1];
    float* out = (float*)d_out;

    __hip_bfloat16* zb = (__hip_bfloat16*)d_ws;                         // 2 MB
    float* lpart = (float*)((char*)d_ws + (size_t)NTOT * DD * 2);       // 1 MB (8192 x 32)

    hipMemsetAsync(d_out, 0, sizeof(float), stream);
    nrm_kernel<<<NTOT / 4, 256, 0, stream>>>(zi, zj, zb);
    sim_kernel<<<dim3(32, 32), 256, 0, stream>>>(zb, lpart);
    fin_kernel<<<NTOT / 256, 256, 0, stream>>>(zb, lpart, out);
}

// Round 2
// 83.199 us; speedup vs baseline: 1.0777x; 1.0777x over previous
//
#include <hip/hip_runtime.h>
#include <hip/hip_bf16.h>

using short8  = __attribute__((ext_vector_type(8))) short;   // 8 bf16 (4 VGPRs)
using floatx4 = __attribute__((ext_vector_type(4))) float;   // 4 fp32 acc

#define B_ROWS 4096
#define NTOT   8192
#define DD     128
#define SQRTC1 1.6986436f            // sqrt(2*log2(e)) — pre-scale so MFMA yields C1*dot
#define E2f    7.389056098930650f    // exp(2): diagonal term (self-dot) to subtract
#define LN2f   0.6931471805599453f   // 2p = d' * ln2  (d' = C1 * p)

// async global->LDS DMA, 16B per lane; LDS dest must be wave-uniform base + lane*16
#define GLOAD_LDS16(gptr, lptr)                                                          \
    __builtin_amdgcn_global_load_lds((const __attribute__((address_space(1))) void*)(gptr), \
                                     (__attribute__((address_space(3))) void*)(lptr), 16, 0, 0)

// ---------------- kernel 1: L2-normalize rows, scale by sqrt(C1), cast bf16 ----------------
// One wave = 2 rows (32 lanes/row, float4 loads = 16B/lane). Also zeroes `out`
// (replaces the hipMemsetAsync dispatch; fin's atomics are stream-ordered after us).
__global__ __launch_bounds__(256) void nrm_kernel(const float* __restrict__ zi,
                                                  const float* __restrict__ zj,
                                                  __hip_bfloat16* __restrict__ zb,
                                                  float* __restrict__ out) {
    int tid  = threadIdx.x;
    if (blockIdx.x == 0 && tid == 0) *out = 0.f;
    int wave = tid >> 6, lane = tid & 63;
    int half = lane >> 5, l32 = lane & 31;
    int row  = blockIdx.x * 8 + wave * 2 + half;
    const float* src = (row < B_ROWS) ? (zi + (size_t)row * DD)
                                      : (zj + (size_t)(row - B_ROWS) * DD);
    float4 v = *(const float4*)(src + l32 * 4);
    float s = v.x * v.x + v.y * v.y + v.z * v.z + v.w * v.w;
    #pragma unroll
    for (int m = 1; m <= 16; m <<= 1) s += __shfl_xor(s, m, 64);   // reduces within 32-lane half
    float scale = SQRTC1 / fmaxf(sqrtf(s), 1e-12f);
    __hip_bfloat162 p0, p1;
    p0.x = __float2bfloat16(v.x * scale); p0.y = __float2bfloat16(v.y * scale);
    p1.x = __float2bfloat16(v.z * scale); p1.y = __float2bfloat16(v.w * scale);
    uint2 u; u.x = *(unsigned*)&p0; u.y = *(unsigned*)&p1;
    *(uint2*)(zb + (size_t)row * DD + l32 * 4) = u;                // one 8B store
}

// ---------------- kernel 2: fused sim-GEMM + partial sum of exp2 ----------------
// grid (32 row-tiles, 32 col-splits); block 256 = 4 waves. Block tile 256x256.
// Wave w: rows [r0+w*64, +64) as 4 row-fragments, full K=128 resident (64 VGPRs).
// B tiles (64 cols) DMA'd to LDS via global_load_lds, double-buffered, 1 barrier/tile.
//
// LDS layout [col][chunk16B ^ (col&7)]  (slot = col*16 + (chunk ^ (col&7))):
//  - staging: slot s=tid+256*rr -> col=s>>4, chunk'=s&15, global chunk=chunk'^((tid>>4)&7).
//    Each 16-lane group reads one CONTIGUOUS 256B row of zb -> fully coalesced DMA
//    (previous layout gathered 64 x 16B at 256B stride per instruction).
//  - read: lane(q,n16) needs col=st*16+n16, chunk=kc*4+q -> slot swizzle makes the
//    ds_read_b128 bank-quad = ((kc<<2|q)^(n16&7))&7, 2-way across a 16-lane group (free).
//  Source permutation == read permutation (both-sides XOR involution; LDS dest stays
//  linear as global_load_lds requires).
__global__ __launch_bounds__(256, 4) void sim_kernel(const __hip_bfloat16* __restrict__ zbf,
                                                     float* __restrict__ lpart) {
    __shared__ uint4 ldsB[2][1024];     // 2 x 16 KB
    const short* zs = (const short*)zbf;

    int tid = threadIdx.x;
    int w   = tid >> 6, lane = tid & 63;
    int q   = lane >> 4, n16 = lane & 15;
    int n7  = n16 & 7;
    int r0  = blockIdx.x * 256 + w * 64;
    int cq  = blockIdx.y;

    // A fragments: rows r0+rs*16+n16, k-chunk kc: m = lane&15, k = (lane>>4)*8 + j
    short8 af[4][4];
    #pragma unroll
    for (int rs = 0; rs < 4; ++rs) {
        const short* ap = zs + (size_t)(r0 + rs * 16 + n16) * DD + q * 8;
        #pragma unroll
        for (int kc = 0; kc < 4; ++kc)
            af[rs][kc] = *(const short8*)(ap + kc * 32);
    }

    // staging source (coalesced): thread tid covers col (tid>>4)+16*rr of the tile,
    // 16B chunk ((tid&15)^((tid>>4)&7)) of that row — rr/t only shift the row index.
    int gc  = tid >> 4;                               // 0..15
    int gk8 = ((tid & 15) ^ (gc & 7)) * 8;            // short offset within row
    const short* gbase = zs + (size_t)(cq * 256 + gc) * DD + gk8;

    float l[4][4];
    #pragma unroll
    for (int rs = 0; rs < 4; ++rs)
        #pragma unroll
        for (int r = 0; r < 4; ++r) l[rs][r] = 0.f;

    // prologue: stage tile 0 into buf 0
    #pragma unroll
    for (int rr = 0; rr < 4; ++rr)
        GLOAD_LDS16(gbase + (size_t)(rr * 16) * DD, &ldsB[0][tid + 256 * rr]);
    __syncthreads();   // compiler drains vmcnt before s_barrier

    #pragma unroll
    for (int t = 0; t < 4; ++t) {
        // issue next tile's DMA into the other buffer (overlaps with compute below)
        if (t < 3) {
            const short* gn = gbase + (size_t)((t + 1) * 64) * DD;
            #pragma unroll
            for (int rr = 0; rr < 4; ++rr)
                GLOAD_LDS16(gn + (size_t)(rr * 16) * DD, &ldsB[(t + 1) & 1][tid + 256 * rr]);
        }
        const uint4* Lb = ldsB[t & 1];
        #pragma unroll
        for (int st = 0; st < 4; ++st) {
            floatx4 acc[4];
            #pragma unroll
            for (int rs = 0; rs < 4; ++rs) acc[rs] = (floatx4){0.f, 0.f, 0.f, 0.f};
            #pragma unroll
            for (int kc = 0; kc < 4; ++kc) {
                // B frag: col = st*16+n16, chunk = kc*4+q, slot = col*16 + (chunk^(n16&7))
                short8 bf = *(const short8*)&Lb[((st * 16 + n16) << 4) + (((kc << 2) | q) ^ n7)];
                #pragma unroll
                for (int rs = 0; rs < 4; ++rs)
                    acc[rs] = __builtin_amdgcn_mfma_f32_16x16x32_bf16(af[rs][kc], bf, acc[rs], 0, 0, 0);
            }
            // epilogue: exp2 + add per element (C layout: row = q*4+r, col = n16)
            #pragma unroll
            for (int rs = 0; rs < 4; ++rs)
                #pragma unroll
                for (int r = 0; r < 4; ++r)
                    l[rs][r] += __builtin_amdgcn_exp2f(acc[rs][r]);
        }
        __syncthreads();   // drains next tile's DMA + releases this buffer
    }

    // reduce the 16 column-lanes (lanes sharing q hold the same 4 rows)
    #pragma unroll
    for (int rs = 0; rs < 4; ++rs)
        #pragma unroll
        for (int r = 0; r < 4; ++r) {
            float v = l[rs][r];
            v += __shfl_xor(v, 1, 64);
            v += __shfl_xor(v, 2, 64);
            v += __shfl_xor(v, 4, 64);
            v += __shfl_xor(v, 8, 64);
            l[rs][r] = v;
        }
    if (n16 == 0) {
        #pragma unroll
        for (int rs = 0; rs < 4; ++rs)
            #pragma unroll
            for (int r = 0; r < 4; ++r) {
                int row = r0 + rs * 16 + q * 4 + r;
                lpart[row * 32 + cq] = l[rs][r];
            }
    }
}

// ---------------- kernel 3: finalize ----------------
// 4 threads per row (128 blocks — was 32): each thread sums 8 lpart entries + 32-dim
// slice of the positive-pair dot, combines via 2 shfl_xor. All 4 lanes then hold the
// full row loss; block-reduce sums 4x oversampled -> scale by 1/(4*NTOT).
__global__ __launch_bounds__(256) void fin_kernel(const __hip_bfloat16* __restrict__ zbf,
                                                  const float* __restrict__ lpart,
                                                  float* __restrict__ out) {
    __shared__ float red[256];
    int tid = threadIdx.x;
    int row = blockIdx.x * 64 + (tid >> 2);
    int sub = tid & 3;

    const float4* lp = (const float4*)(lpart + row * 32 + sub * 8);
    float4 v0 = lp[0], v1 = lp[1];
    float l = (v0.x + v0.y) + (v0.z + v0.w) + (v1.x + v1.y) + (v1.z + v1.w);

    const __hip_bfloat162* a = (const __hip_bfloat162*)(zbf + (size_t)row * DD + sub * 32);
    const __hip_bfloat162* b = (const __hip_bfloat162*)(zbf + (size_t)(row ^ B_ROWS) * DD + sub * 32);
    float d = 0.f;
    #pragma unroll
    for (int i = 0; i < 16; ++i) {
        float2 av = __bfloat1622float2(a[i]);
        float2 bv = __bfloat1622float2(b[i]);
        d += av.x * bv.x + av.y * bv.y;
    }

    // combine the 4 sub-lanes (masks 1,2 stay within the 4-lane group)
    l += __shfl_xor(l, 1, 64); l += __shfl_xor(l, 2, 64);
    d += __shfl_xor(d, 1, 64); d += __shfl_xor(d, 2, 64);

    float loss = -d * LN2f + logf(l - E2f);
    red[tid] = loss;
    __syncthreads();
    #pragma unroll
    for (int s = 128; s > 0; s >>= 1) {
        if (tid < s) red[tid] += red[tid + s];
        __syncthreads();
    }
    if (tid == 0) atomicAdd(out, red[0] * (1.0f / (4.0f * (float)NTOT)));
}

extern "C" void kernel_launch(void* const* d_in, const int* in_sizes, int n_in,
                              void* d_out, int out_size, void* d_ws, size_t ws_size,
                              hipStream_t stream) {
    const float* zi = (const float*)d_in[0];
    const float* zj = (const float*)d_in[1];
    float* out = (float*)d_out;

    __hip_bfloat16* zb = (__hip_bfloat16*)d_ws;                         // 2 MB
    float* lpart = (float*)((char*)d_ws + (size_t)NTOT * DD * 2);       // 1 MB (8192 x 32)

    nrm_kernel<<<NTOT / 8, 256, 0, stream>>>(zi, zj, zb, out);          // also zeroes out
    sim_kernel<<<dim3(32, 32), 256, 0, stream>>>(zb, lpart);
    fin_kernel<<<NTOT / 64, 256, 0, stream>>>(zb, lpart, out);
}